// Round 9
// baseline (293.480 us; speedup 1.0000x reference)
//
#include <hip/hip_runtime.h>

// Problem constants (fp32 RQ-VAE nearest-codebook step)
#define Bn 8192
#define Kn 8192
#define Dn 512
#define WINDOW 0.25f   // refine window: covers f16-noise + 8-bit mantissa packing

typedef _Float16 half8 __attribute__((ext_vector_type(8)));
typedef float floatx4 __attribute__((ext_vector_type(4)));
typedef unsigned long long u64;

// Order-preserving map float -> u32 (monotone under unsigned compare, finite inputs)
__device__ __forceinline__ unsigned int fkey(float f) {
    unsigned int u = __float_as_uint(f);
    return (u & 0x80000000u) ? ~u : (u | 0x80000000u);
}

// async global->LDS, 16B per lane (global_load_lds_dwordx4)
__device__ __forceinline__ void gld16(const _Float16* g, _Float16* l) {
    __builtin_amdgcn_global_load_lds(
        (const __attribute__((address_space(1))) unsigned int*)g,
        (__attribute__((address_space(3))) unsigned int*)l, 16, 0, 0);
}

// ---------------- kernel: e_sq (fallback path only) ----------------
__global__ __launch_bounds__(256) void esq_kernel(const float* __restrict__ E,
                                                  float* __restrict__ esq) {
    int wave = threadIdx.x >> 6;
    int lane = threadIdx.x & 63;
    int k = blockIdx.x * 4 + wave;
    const float4* row = (const float4*)(E + (size_t)k * Dn);
    float4 v0 = row[lane];
    float4 v1 = row[64 + lane];
    float s = v0.x*v0.x + v0.y*v0.y + v0.z*v0.z + v0.w*v0.w
            + v1.x*v1.x + v1.y*v1.y + v1.z*v1.z + v1.w*v1.w;
    #pragma unroll
    for (int off = 32; off > 0; off >>= 1) s += __shfl_down(s, off, 64);
    if (lane == 0) esq[k] = s;
}

// ---------------- kernel: fp32 -> f16 (hi), PACKED layout, + fused e_sq ------
// G[panel][chunk][slot]*8 halves, panel = 128 rows, chunk = 32 k-halves,
//   slot(row128, kq) = (row128>>6)*256 + ((row128>>4)&3)*64 + kq*16 + (row128&15)
// blocks [0,1024) pack X, [1024,2048) pack E (E blocks also atomicAdd e_sq
// partials; esq must be zeroed before launch).
__global__ __launch_bounds__(256) void convert_hi(
    const float* __restrict__ X, const float* __restrict__ E,
    _Float16* __restrict__ Xh, _Float16* __restrict__ Eh,
    float* __restrict__ esq)
{
    const bool isE = blockIdx.x >= 1024;
    const int pc = blockIdx.x & 1023;
    const int panel = pc >> 4;              // 64 panels of 128 rows
    const int chunk = pc & 15;              // 16 chunks of 32 halves
    const float* src = isE ? E : X;
    _Float16* dst = isE ? Eh : Xh;
    const int t = threadIdx.x;
    const int row = t >> 1;                 // [0,128)
    const int kh  = (t & 1) * 16;
    const float* p = &src[(size_t)(panel * 128 + row) * Dn + chunk * 32 + kh];
    float4 v[4];
    v[0] = *(const float4*)(p + 0);
    v[1] = *(const float4*)(p + 4);
    v[2] = *(const float4*)(p + 8);
    v[3] = *(const float4*)(p + 12);
    const int slotbase = ((row >> 6) << 8) + (((row >> 4) & 3) << 6) + (row & 15);
    #pragma unroll
    for (int j = 0; j < 2; ++j) {
        half8 h;
        #pragma unroll
        for (int q = 0; q < 2; ++q) {
            const float4 w = v[j * 2 + q];
            h[q*4+0]=(_Float16)w.x; h[q*4+1]=(_Float16)w.y;
            h[q*4+2]=(_Float16)w.z; h[q*4+3]=(_Float16)w.w;
        }
        const int kq = (t & 1) * 2 + j;
        const size_t off = ((size_t)(panel * 16 + chunk) * 512
                            + slotbase + kq * 16) * 8;
        *(half8*)&dst[off] = h;
    }
    if (isE) {
        float s = 0.f;
        #pragma unroll
        for (int i = 0; i < 4; ++i)
            s += v[i].x*v[i].x + v[i].y*v[i].y + v[i].z*v[i].z + v[i].w*v[i].w;
        s += __shfl_xor(s, 1);              // pair (kh=0, kh=16) -> 32-col partial
        if ((t & 1) == 0) atomicAdd(&esq[panel * 128 + row], s);
    }
}

// ---------------- kernel: hi-only MFMA, NT=4 n-tiles, packed-float top-2 -----
// d~(b,k) = e_sq[k] - 2*(xh.eh). Block = 128 rows x 512 cols (4 n-tiles of
// 128), 4 waves of 64x64 per tile. XCD-aware bid swizzle: each XCD keeps only
// 2 rg's E panels (1MB, L2-resident) and streams X. Per-thread RUNNING top-2
// (fp32 keys, 8-bit candidate id in low mantissa) across the 4 tiles; single
// 16-lane butterfly at the end. Store: 4 floats per (row, 512-col region).
__global__ __launch_bounds__(256, 5) void argmin_hi(
    const _Float16* __restrict__ Xh, const _Float16* __restrict__ Eh,
    const float* __restrict__ esq, float* __restrict__ bestf)
{
    __shared__ __align__(16) _Float16 sX[8192];   // 128 rows x 64 k-halves
    __shared__ __align__(16) _Float16 sE[8192];

    const int tid  = threadIdx.x;
    const int bid  = blockIdx.x;
    const int lid  = bid >> 3;
    const int rg   = (bid & 7) | ((lid & 1) << 3);   // 16 col-regions of 512
    const int mb   = lid >> 1;                        // 64 m-blocks
    const int m0   = mb * 128, n0 = rg * 512;
    const int lane = tid & 63, wave = tid >> 6;
    const int wx   = wave & 1, wy = wave >> 1;
    const int colg = lane & 15, quad = lane >> 4;

    float v1[16], v2[16];                  // running top-2 per (mi,r)
    #pragma unroll
    for (int i = 0; i < 16; ++i) { v1[i] = INFINITY; v2[i] = INFINITY; }

    const _Float16* gX = Xh + (size_t)mb * 65536 + tid * 8;
    _Float16* dX = &sX[tid * 8];
    _Float16* dE = &sE[tid * 8];
    const int aoff = wy * 2048 + lane * 8;   // + s*4096 + mi*512
    const int boff = wx * 2048 + lane * 8;   // + s*4096 + ni*512
    const unsigned colg4 = (unsigned)colg << 4;

    for (int nt = 0; nt < 4; ++nt) {
        const _Float16* gE = Eh + (size_t)(rg * 4 + nt) * 65536 + tid * 8;
        floatx4 acc[4][4];
        #pragma unroll
        for (int i = 0; i < 4; ++i)
            #pragma unroll
            for (int j = 0; j < 4; ++j) acc[i][j] = {0.f, 0.f, 0.f, 0.f};

        for (int c = 0; c < 8; ++c) {        // 8 x BK=64 halves
            const size_t gb = (size_t)c * 8192;
            __syncthreads();                 // prev iteration's LDS reads done
            gld16(gX + gb,        dX);
            gld16(gX + gb + 2048, dX + 2048);
            gld16(gX + gb + 4096, dX + 4096);
            gld16(gX + gb + 6144, dX + 6144);
            gld16(gE + gb,        dE);
            gld16(gE + gb + 2048, dE + 2048);
            gld16(gE + gb + 4096, dE + 4096);
            gld16(gE + gb + 6144, dE + 6144);
            __syncthreads();                 // drains vmcnt -> data visible

            #pragma unroll
            for (int s = 0; s < 2; ++s) {    // 2 k-steps of 32 halves
                const int so = s * 4096;
                half8 bh[4];
                #pragma unroll
                for (int ni = 0; ni < 4; ++ni)
                    bh[ni] = *(const half8*)&sE[boff + so + ni * 512];
                #pragma unroll
                for (int mi = 0; mi < 4; ++mi) {
                    half8 ah = *(const half8*)&sX[aoff + so + mi * 512];
                    #pragma unroll
                    for (int ni = 0; ni < 4; ++ni)
                        acc[mi][ni] = __builtin_amdgcn_mfma_f32_16x16x32_f16(
                            ah, bh[ni], acc[mi][ni], 0, 0, 0);
                }
            }
        }

        // fold this n-tile into running top-2 (C/D: col=lane&15, row=quad*4+reg)
        float eq[4];
        #pragma unroll
        for (int ni = 0; ni < 4; ++ni)
            eq[ni] = esq[n0 + nt * 128 + wx * 64 + ni * 16 + colg];
        #pragma unroll
        for (int mi = 0; mi < 4; ++mi)
            #pragma unroll
            for (int r = 0; r < 4; ++r) {
                const int i = mi * 4 + r;
                #pragma unroll
                for (int ni = 0; ni < 4; ++ni) {
                    const float dv = eq[ni] - 2.0f * acc[mi][ni][r];
                    const unsigned ob = colg4 | (unsigned)((nt << 2) | ni);
                    const float key = __uint_as_float(
                        (__float_as_uint(dv) & 0xFFFFFF00u) | ob);
                    v2[i] = fminf(v2[i], fmaxf(v1[i], key));
                    v1[i] = fminf(v1[i], key);
                }
            }
    }

    // one butterfly per (mi,r): merge 16 lanes' top-2, store 2 floats
    #pragma unroll
    for (int mi = 0; mi < 4; ++mi)
        #pragma unroll
        for (int r = 0; r < 4; ++r) {
            const int i = mi * 4 + r;
            float a1 = v1[i], a2 = v2[i];
            #pragma unroll
            for (int off = 1; off < 16; off <<= 1) {
                const float p1 = __shfl_xor(a1, off);
                const float p2 = __shfl_xor(a2, off);
                a2 = fminf(fmaxf(a1, p1), fminf(a2, p2));
                a1 = fminf(a1, p1);
            }
            if (colg == 0) {
                const int row = m0 + wy * 64 + mi * 16 + quad * 4 + r;
                float2 st; st.x = a1; st.y = a2;
                *(float2*)&bestf[(size_t)row * 64 + rg * 4 + wx * 2] = st;
            }
        }
}

// ---------------- kernel: exact refine, ONE WAVE PER ROW ---------------------
// 64 lanes read the row's 64 stored keys, wave-min -> threshold -> ballot
// survivors -> exact fp32 distance (sum e*(e-2x)) per survivor -> best index
// (u64 key: ties to lowest index) -> write index + residual. No LDS/atomics.
__global__ __launch_bounds__(256) void refine_kernel(
    const float* __restrict__ X, const float* __restrict__ E,
    const float* __restrict__ bestf, float* __restrict__ out)
{
    const int lane = threadIdx.x & 63, wave = threadIdx.x >> 6;
    const int b = blockIdx.x * 4 + wave;

    const float val = bestf[(size_t)b * 64 + lane];
    // decode this slot's candidate column
    const unsigned bits = __float_as_uint(val);
    const int rg = lane >> 2, wx = (lane >> 1) & 1;
    const int colg = (bits >> 4) & 15, nt = (bits >> 2) & 3, ni = bits & 3;
    const int col = rg * 512 + nt * 128 + wx * 64 + ni * 16 + colg;

    float mn = val;
    #pragma unroll
    for (int off = 1; off < 64; off <<= 1) mn = fminf(mn, __shfl_xor(mn, off));

    const float4* xr = (const float4*)(X + (size_t)b * Dn);
    const float4 x0 = xr[lane * 2], x1 = xr[lane * 2 + 1];

    u64 bestk = ~0ull;
    u64 mask = __ballot(val <= mn + WINDOW);
    while (mask) {
        const int s = __builtin_ctzll(mask);
        mask &= mask - 1;
        const int c = __shfl(col, s);
        const float4* er = (const float4*)(E + (size_t)c * Dn);
        const float4 e0 = er[lane * 2], e1 = er[lane * 2 + 1];
        float p = e0.x*(e0.x - 2.f*x0.x) + e0.y*(e0.y - 2.f*x0.y)
                + e0.z*(e0.z - 2.f*x0.z) + e0.w*(e0.w - 2.f*x0.w)
                + e1.x*(e1.x - 2.f*x1.x) + e1.y*(e1.y - 2.f*x1.y)
                + e1.z*(e1.z - 2.f*x1.z) + e1.w*(e1.w - 2.f*x1.w);
        #pragma unroll
        for (int off = 1; off < 64; off <<= 1) p += __shfl_xor(p, off);
        const u64 k = ((u64)fkey(p) << 32) | (u64)(unsigned int)c;
        if (k < bestk) bestk = k;
    }

    const int idx = (int)(unsigned int)(bestk & 0xFFFFFFFFull);
    if (lane == 0) out[b] = (float)idx;
    const float4* er = (const float4*)(E + (size_t)idx * Dn);
    const float4 e0 = er[lane * 2], e1 = er[lane * 2 + 1];
    float4 r0, r1;
    r0.x = x0.x - e0.x; r0.y = x0.y - e0.y; r0.z = x0.z - e0.z; r0.w = x0.w - e0.w;
    r1.x = x1.x - e1.x; r1.y = x1.y - e1.y; r1.z = x1.z - e1.z; r1.w = x1.w - e1.w;
    float4* o = (float4*)(out + Bn + (size_t)b * Dn);
    o[lane * 2] = r0; o[lane * 2 + 1] = r1;
}

// ---------------- fallback (round-1 fp32 path, used only if ws too small) ----
#define KSPLIT 16
#define LDSW 132
__global__ __launch_bounds__(256, 2) void argmin_fp32(
    const float* __restrict__ X, const float* __restrict__ E,
    const float* __restrict__ esq, u64* __restrict__ best)
{
    __shared__ __align__(16) float Xs[16][LDSW];
    __shared__ __align__(16) float Es[16][LDSW];
    __shared__ u64 red[128][16];
    const int tid = threadIdx.x;
    const int tx = tid & 15, ty = tid >> 4;
    const int rowTile = blockIdx.x / KSPLIT;
    const int split   = blockIdx.x % KSPLIT;
    const int m0 = rowTile * 128;
    const int kbase = split * (Kn / KSPLIT);
    float bestv[8]; int besti[8];
    #pragma unroll
    for (int i = 0; i < 8; ++i) { bestv[i] = INFINITY; besti[i] = 0; }
    const int ldRow = tid >> 2, ldD = (tid & 3) * 4;
    for (int kt = 0; kt < (Kn / KSPLIT) / 128; ++kt) {
        const int k0 = kbase + kt * 128;
        float acc[8][8] = {};
        for (int dc = 0; dc < Dn / 16; ++dc) {
            const int d0 = dc * 16;
            float4 xa = *(const float4*)&X[(size_t)(m0 + ldRow)      * Dn + d0 + ldD];
            float4 xb = *(const float4*)&X[(size_t)(m0 + 64 + ldRow) * Dn + d0 + ldD];
            float4 ea = *(const float4*)&E[(size_t)(k0 + ldRow)      * Dn + d0 + ldD];
            float4 eb = *(const float4*)&E[(size_t)(k0 + 64 + ldRow) * Dn + d0 + ldD];
            __syncthreads();
            Xs[ldD+0][ldRow] = xa.x; Xs[ldD+1][ldRow] = xa.y;
            Xs[ldD+2][ldRow] = xa.z; Xs[ldD+3][ldRow] = xa.w;
            Xs[ldD+0][64+ldRow] = xb.x; Xs[ldD+1][64+ldRow] = xb.y;
            Xs[ldD+2][64+ldRow] = xb.z; Xs[ldD+3][64+ldRow] = xb.w;
            Es[ldD+0][ldRow] = ea.x; Es[ldD+1][ldRow] = ea.y;
            Es[ldD+2][ldRow] = ea.z; Es[ldD+3][ldRow] = ea.w;
            Es[ldD+0][64+ldRow] = eb.x; Es[ldD+1][64+ldRow] = eb.y;
            Es[ldD+2][64+ldRow] = eb.z; Es[ldD+3][64+ldRow] = eb.w;
            __syncthreads();
            #pragma unroll
            for (int d = 0; d < 16; ++d) {
                float a8[8], b8[8];
                *(float4*)&a8[0] = *(const float4*)&Xs[d][4*ty];
                *(float4*)&a8[4] = *(const float4*)&Xs[d][64 + 4*ty];
                *(float4*)&b8[0] = *(const float4*)&Es[d][4*tx];
                *(float4*)&b8[4] = *(const float4*)&Es[d][64 + 4*tx];
                #pragma unroll
                for (int i = 0; i < 8; ++i)
                    #pragma unroll
                    for (int j = 0; j < 8; ++j) acc[i][j] += a8[i] * b8[j];
            }
        }
        #pragma unroll
        for (int j = 0; j < 8; ++j) {
            const int c = k0 + ((j < 4) ? (4*tx + j) : (64 + 4*tx + (j - 4)));
            const float eq = esq[c];
            #pragma unroll
            for (int i = 0; i < 8; ++i) {
                float dval = eq - 2.0f * acc[i][j];
                if (dval < bestv[i]) { bestv[i] = dval; besti[i] = c; }
            }
        }
    }
    #pragma unroll
    for (int i = 0; i < 8; ++i) {
        int rloc = (i < 4) ? (4*ty + i) : (64 + 4*ty + (i - 4));
        red[rloc][tx] = ((u64)fkey(bestv[i]) << 32) | (u64)(unsigned int)besti[i];
    }
    __syncthreads();
    if (tid < 128) {
        u64 m = red[tid][0];
        #pragma unroll
        for (int t = 1; t < 16; ++t) { u64 v = red[tid][t]; if (v < m) m = v; }
        best[(size_t)(m0 + tid) * KSPLIT + split] = m;
    }
}

__global__ __launch_bounds__(256) void finalize_kernel(
    const float* __restrict__ X, const float* __restrict__ E,
    const u64* __restrict__ best, float* __restrict__ out, int nsplits)
{
    __shared__ int sidx[2];
    const int half = threadIdx.x >> 7;
    const int t    = threadIdx.x & 127;
    const int b    = blockIdx.x * 2 + half;
    if (t < 64) {
        u64 v = (t < nsplits) ? best[(size_t)b * nsplits + t] : ~0ull;
        #pragma unroll
        for (int off = 1; off < 64; off <<= 1) {
            u64 o = __shfl_xor(v, off);
            if (o < v) v = o;
        }
        if (t == 0) {
            int idx = (int)(unsigned int)(v & 0xFFFFFFFFull);
            sidx[half] = idx;
            out[b] = (float)idx;
        }
    }
    __syncthreads();
    const int idx = sidx[half];
    float4 x = ((const float4*)(X + (size_t)b * Dn))[t];
    float4 e = ((const float4*)(E + (size_t)idx * Dn))[t];
    float4 r; r.x = x.x - e.x; r.y = x.y - e.y; r.z = x.z - e.z; r.w = x.w - e.w;
    ((float4*)(out + Bn + (size_t)b * Dn))[t] = r;
}

extern "C" void kernel_launch(void* const* d_in, const int* in_sizes, int n_in,
                              void* d_out, int out_size, void* d_ws, size_t ws_size,
                              hipStream_t stream) {
    const float* X = (const float*)d_in[0];   // previous_residual [B, D]
    const float* E = (const float*)d_in[1];   // codebook_embeddings [K, D]
    float* out = (float*)d_out;               // [B] idx-as-float ++ [B*D] residual

    // fast-path ws: esq 32KB | Xh 8MB | Eh 8MB | bestf 2MB  (~18.3 MB)
    const size_t HB = (size_t)Bn * Dn * sizeof(_Float16);        // 8 MB
    const size_t BESTB = (size_t)Bn * 64 * sizeof(float);        // 2 MB
    const size_t NEED = 32768 + 2 * HB + BESTB;

    float* esq = (float*)d_ws;

    if (ws_size >= NEED) {
        _Float16* Xh = (_Float16*)((char*)d_ws + 32768);
        _Float16* Eh = (_Float16*)((char*)d_ws + 32768 + HB);
        float* bestf = (float*)((char*)d_ws + 32768 + 2 * HB);
        hipMemsetAsync((void*)esq, 0, Kn * sizeof(float), stream);
        convert_hi<<<2048, 256, 0, stream>>>(X, E, Xh, Eh, esq);
        argmin_hi<<<64 * 16, 256, 0, stream>>>(Xh, Eh, esq, bestf);
        refine_kernel<<<Bn / 4, 256, 0, stream>>>(X, E, bestf, out);
    } else {
        u64* best = (u64*)((char*)d_ws + 32768);
        esq_kernel<<<Kn / 4, 256, 0, stream>>>(E, esq);
        argmin_fp32<<<(Bn / 128) * KSPLIT, 256, 0, stream>>>(X, E, esq, best);
        finalize_kernel<<<Bn / 2, 256, 0, stream>>>(X, E, best, out, KSPLIT);
    }
}

// Round 10
// 172.725 us; speedup vs baseline: 1.6991x; 1.6991x over previous
//
#include <hip/hip_runtime.h>

// Problem constants (fp32 RQ-VAE nearest-codebook step)
#define Bn 8192
#define Kn 8192
#define Dn 512
#define WINDOW 0.25f   // refine window: covers f16-noise + 8-bit mantissa packing

typedef _Float16 half8 __attribute__((ext_vector_type(8)));
typedef float floatx4 __attribute__((ext_vector_type(4)));
typedef unsigned long long u64;

// Order-preserving map float -> u32 (monotone under unsigned compare, finite inputs)
__device__ __forceinline__ unsigned int fkey(float f) {
    unsigned int u = __float_as_uint(f);
    return (u & 0x80000000u) ? ~u : (u | 0x80000000u);
}

// async global->LDS, 16B per lane (global_load_lds_dwordx4)
__device__ __forceinline__ void gld16(const _Float16* g, _Float16* l) {
    __builtin_amdgcn_global_load_lds(
        (const __attribute__((address_space(1))) unsigned int*)g,
        (__attribute__((address_space(3))) unsigned int*)l, 16, 0, 0);
}

// ---------------- kernel: e_sq (fallback path only) ----------------
__global__ __launch_bounds__(256) void esq_kernel(const float* __restrict__ E,
                                                  float* __restrict__ esq) {
    int wave = threadIdx.x >> 6;
    int lane = threadIdx.x & 63;
    int k = blockIdx.x * 4 + wave;
    const float4* row = (const float4*)(E + (size_t)k * Dn);
    float4 v0 = row[lane];
    float4 v1 = row[64 + lane];
    float s = v0.x*v0.x + v0.y*v0.y + v0.z*v0.z + v0.w*v0.w
            + v1.x*v1.x + v1.y*v1.y + v1.z*v1.z + v1.w*v1.w;
    #pragma unroll
    for (int off = 32; off > 0; off >>= 1) s += __shfl_down(s, off, 64);
    if (lane == 0) esq[k] = s;
}

// ---------------- kernel: fp32 -> f16 (hi), PACKED layout, + fused e_sq ------
// G[panel][chunk][slot]*8 halves, panel = 128 rows, chunk = 32 k-halves,
//   slot(row128, kq) = (row128>>6)*256 + ((row128>>4)&3)*64 + kq*16 + (row128&15)
// blocks [0,1024) pack X, [1024,2048) pack E (E blocks also atomicAdd e_sq
// partials; esq must be zeroed before launch).
__global__ __launch_bounds__(256) void convert_hi(
    const float* __restrict__ X, const float* __restrict__ E,
    _Float16* __restrict__ Xh, _Float16* __restrict__ Eh,
    float* __restrict__ esq)
{
    const bool isE = blockIdx.x >= 1024;
    const int pc = blockIdx.x & 1023;
    const int panel = pc >> 4;              // 64 panels of 128 rows
    const int chunk = pc & 15;              // 16 chunks of 32 halves
    const float* src = isE ? E : X;
    _Float16* dst = isE ? Eh : Xh;
    const int t = threadIdx.x;
    const int row = t >> 1;                 // [0,128)
    const int kh  = (t & 1) * 16;
    const float* p = &src[(size_t)(panel * 128 + row) * Dn + chunk * 32 + kh];
    float4 v[4];
    v[0] = *(const float4*)(p + 0);
    v[1] = *(const float4*)(p + 4);
    v[2] = *(const float4*)(p + 8);
    v[3] = *(const float4*)(p + 12);
    const int slotbase = ((row >> 6) << 8) + (((row >> 4) & 3) << 6) + (row & 15);
    #pragma unroll
    for (int j = 0; j < 2; ++j) {
        half8 h;
        #pragma unroll
        for (int q = 0; q < 2; ++q) {
            const float4 w = v[j * 2 + q];
            h[q*4+0]=(_Float16)w.x; h[q*4+1]=(_Float16)w.y;
            h[q*4+2]=(_Float16)w.z; h[q*4+3]=(_Float16)w.w;
        }
        const int kq = (t & 1) * 2 + j;
        const size_t off = ((size_t)(panel * 16 + chunk) * 512
                            + slotbase + kq * 16) * 8;
        *(half8*)&dst[off] = h;
    }
    if (isE) {
        float s = 0.f;
        #pragma unroll
        for (int i = 0; i < 4; ++i)
            s += v[i].x*v[i].x + v[i].y*v[i].y + v[i].z*v[i].z + v[i].w*v[i].w;
        s += __shfl_xor(s, 1);              // pair (kh=0, kh=16) -> 32-col partial
        if ((t & 1) == 0) atomicAdd(&esq[panel * 128 + row], s);
    }
}

// ---------------- kernel: hi-only MFMA, BK=128, NT=4, packed-float top-2 -----
// d~(b,k) = e_sq[k] - 2*(xh.eh). Block = 128 rows x 512 cols (4 n-tiles of
// 128), 4 waves of 64x64 per tile. BK=128 staging (64KB LDS, 2 blocks/CU):
// 64 MFMA/wave per barrier interval -- 2x compute-per-drain vs BK=64, and the
// co-resident block's compute covers this block's vmcnt drain.
// __launch_bounds__(256,2): up to 256 unified regs/wave -> NO spills (r9's
// (256,5) capped at ~48 VGPR and spilled 330MB to scratch).
// XCD-aware bid swizzle keeps each XCD's E working set ~1MB (L2-resident).
__global__ __launch_bounds__(256, 2) void argmin_hi(
    const _Float16* __restrict__ Xh, const _Float16* __restrict__ Eh,
    const float* __restrict__ esq, float* __restrict__ bestf)
{
    __shared__ __align__(16) _Float16 sX[16384];   // 128 rows x 128 k-halves
    __shared__ __align__(16) _Float16 sE[16384];

    const int tid  = threadIdx.x;
    const int bid  = blockIdx.x;
    const int lid  = bid >> 3;
    const int rg   = (bid & 7) | ((lid & 1) << 3);   // 16 col-regions of 512
    const int mb   = lid >> 1;                        // 64 m-blocks
    const int m0   = mb * 128, n0 = rg * 512;
    const int lane = tid & 63, wave = tid >> 6;
    const int wx   = wave & 1, wy = wave >> 1;
    const int colg = lane & 15, quad = lane >> 4;

    float v1[16], v2[16];                  // running top-2 per (mi,r)
    #pragma unroll
    for (int i = 0; i < 16; ++i) { v1[i] = INFINITY; v2[i] = INFINITY; }

    const _Float16* gX = Xh + (size_t)mb * 65536 + tid * 8;
    _Float16* dX = &sX[tid * 8];
    _Float16* dE = &sE[tid * 8];
    const int aoff = wy * 2048 + lane * 8;   // + s*4096 + mi*512
    const int boff = wx * 2048 + lane * 8;   // + s*4096 + ni*512
    const unsigned colg4 = (unsigned)colg << 4;

    for (int nt = 0; nt < 4; ++nt) {
        const _Float16* gE = Eh + (size_t)(rg * 4 + nt) * 65536 + tid * 8;
        floatx4 acc[4][4];
        #pragma unroll
        for (int i = 0; i < 4; ++i)
            #pragma unroll
            for (int j = 0; j < 4; ++j) acc[i][j] = {0.f, 0.f, 0.f, 0.f};

        for (int c = 0; c < 4; ++c) {        // 4 x BK=128 halves
            const size_t gb = (size_t)c * 16384;
            __syncthreads();                 // prev interval's LDS reads done
            #pragma unroll
            for (int j = 0; j < 8; ++j) gld16(gX + gb + j * 2048, dX + j * 2048);
            #pragma unroll
            for (int j = 0; j < 8; ++j) gld16(gE + gb + j * 2048, dE + j * 2048);
            __syncthreads();                 // drains vmcnt -> data visible

            #pragma unroll
            for (int s = 0; s < 4; ++s) {    // 4 k-steps of 32 halves
                const int so = s * 4096;
                half8 bh[4];
                #pragma unroll
                for (int ni = 0; ni < 4; ++ni)
                    bh[ni] = *(const half8*)&sE[boff + so + ni * 512];
                #pragma unroll
                for (int mi = 0; mi < 4; ++mi) {
                    half8 ah = *(const half8*)&sX[aoff + so + mi * 512];
                    #pragma unroll
                    for (int ni = 0; ni < 4; ++ni)
                        acc[mi][ni] = __builtin_amdgcn_mfma_f32_16x16x32_f16(
                            ah, bh[ni], acc[mi][ni], 0, 0, 0);
                }
            }
        }

        // fold this n-tile into running top-2 (C/D: col=lane&15, row=quad*4+reg)
        float eq[4];
        #pragma unroll
        for (int ni = 0; ni < 4; ++ni)
            eq[ni] = esq[n0 + nt * 128 + wx * 64 + ni * 16 + colg];
        #pragma unroll
        for (int mi = 0; mi < 4; ++mi)
            #pragma unroll
            for (int r = 0; r < 4; ++r) {
                const int i = mi * 4 + r;
                #pragma unroll
                for (int ni = 0; ni < 4; ++ni) {
                    const float dv = eq[ni] - 2.0f * acc[mi][ni][r];
                    const unsigned ob = colg4 | (unsigned)((nt << 2) | ni);
                    const float key = __uint_as_float(
                        (__float_as_uint(dv) & 0xFFFFFF00u) | ob);
                    v2[i] = fminf(v2[i], fmaxf(v1[i], key));
                    v1[i] = fminf(v1[i], key);
                }
            }
    }

    // one butterfly per (mi,r): merge 16 lanes' top-2, store 2 floats
    #pragma unroll
    for (int mi = 0; mi < 4; ++mi)
        #pragma unroll
        for (int r = 0; r < 4; ++r) {
            const int i = mi * 4 + r;
            float a1 = v1[i], a2 = v2[i];
            #pragma unroll
            for (int off = 1; off < 16; off <<= 1) {
                const float p1 = __shfl_xor(a1, off);
                const float p2 = __shfl_xor(a2, off);
                a2 = fminf(fmaxf(a1, p1), fminf(a2, p2));
                a1 = fminf(a1, p1);
            }
            if (colg == 0) {
                const int row = m0 + wy * 64 + mi * 16 + quad * 4 + r;
                float2 st; st.x = a1; st.y = a2;
                *(float2*)&bestf[(size_t)row * 64 + rg * 4 + wx * 2] = st;
            }
        }
}

// ---------------- kernel: exact refine, ONE WAVE PER ROW ---------------------
// 64 lanes read the row's 64 stored keys, wave-min -> threshold -> ballot
// survivors -> exact fp32 distance (sum e*(e-2x)) per survivor -> best index
// (u64 key: ties to lowest index) -> write index + residual. No LDS/atomics.
__global__ __launch_bounds__(256) void refine_kernel(
    const float* __restrict__ X, const float* __restrict__ E,
    const float* __restrict__ bestf, float* __restrict__ out)
{
    const int lane = threadIdx.x & 63, wave = threadIdx.x >> 6;
    const int b = blockIdx.x * 4 + wave;

    const float val = bestf[(size_t)b * 64 + lane];
    // decode this slot's candidate column
    const unsigned bits = __float_as_uint(val);
    const int rg = lane >> 2, wx = (lane >> 1) & 1;
    const int colg = (bits >> 4) & 15, nt = (bits >> 2) & 3, ni = bits & 3;
    const int col = rg * 512 + nt * 128 + wx * 64 + ni * 16 + colg;

    float mn = val;
    #pragma unroll
    for (int off = 1; off < 64; off <<= 1) mn = fminf(mn, __shfl_xor(mn, off));

    const float4* xr = (const float4*)(X + (size_t)b * Dn);
    const float4 x0 = xr[lane * 2], x1 = xr[lane * 2 + 1];

    u64 bestk = ~0ull;
    u64 mask = __ballot(val <= mn + WINDOW);
    while (mask) {
        const int s = __builtin_ctzll(mask);
        mask &= mask - 1;
        const int c = __shfl(col, s);
        const float4* er = (const float4*)(E + (size_t)c * Dn);
        const float4 e0 = er[lane * 2], e1 = er[lane * 2 + 1];
        float p = e0.x*(e0.x - 2.f*x0.x) + e0.y*(e0.y - 2.f*x0.y)
                + e0.z*(e0.z - 2.f*x0.z) + e0.w*(e0.w - 2.f*x0.w)
                + e1.x*(e1.x - 2.f*x1.x) + e1.y*(e1.y - 2.f*x1.y)
                + e1.z*(e1.z - 2.f*x1.z) + e1.w*(e1.w - 2.f*x1.w);
        #pragma unroll
        for (int off = 1; off < 64; off <<= 1) p += __shfl_xor(p, off);
        const u64 k = ((u64)fkey(p) << 32) | (u64)(unsigned int)c;
        if (k < bestk) bestk = k;
    }

    const int idx = (int)(unsigned int)(bestk & 0xFFFFFFFFull);
    if (lane == 0) out[b] = (float)idx;
    const float4* er = (const float4*)(E + (size_t)idx * Dn);
    const float4 e0 = er[lane * 2], e1 = er[lane * 2 + 1];
    float4 r0, r1;
    r0.x = x0.x - e0.x; r0.y = x0.y - e0.y; r0.z = x0.z - e0.z; r0.w = x0.w - e0.w;
    r1.x = x1.x - e1.x; r1.y = x1.y - e1.y; r1.z = x1.z - e1.z; r1.w = x1.w - e1.w;
    float4* o = (float4*)(out + Bn + (size_t)b * Dn);
    o[lane * 2] = r0; o[lane * 2 + 1] = r1;
}

// ---------------- fallback (round-1 fp32 path, used only if ws too small) ----
#define KSPLIT 16
#define LDSW 132
__global__ __launch_bounds__(256, 2) void argmin_fp32(
    const float* __restrict__ X, const float* __restrict__ E,
    const float* __restrict__ esq, u64* __restrict__ best)
{
    __shared__ __align__(16) float Xs[16][LDSW];
    __shared__ __align__(16) float Es[16][LDSW];
    __shared__ u64 red[128][16];
    const int tid = threadIdx.x;
    const int tx = tid & 15, ty = tid >> 4;
    const int rowTile = blockIdx.x / KSPLIT;
    const int split   = blockIdx.x % KSPLIT;
    const int m0 = rowTile * 128;
    const int kbase = split * (Kn / KSPLIT);
    float bestv[8]; int besti[8];
    #pragma unroll
    for (int i = 0; i < 8; ++i) { bestv[i] = INFINITY; besti[i] = 0; }
    const int ldRow = tid >> 2, ldD = (tid & 3) * 4;
    for (int kt = 0; kt < (Kn / KSPLIT) / 128; ++kt) {
        const int k0 = kbase + kt * 128;
        float acc[8][8] = {};
        for (int dc = 0; dc < Dn / 16; ++dc) {
            const int d0 = dc * 16;
            float4 xa = *(const float4*)&X[(size_t)(m0 + ldRow)      * Dn + d0 + ldD];
            float4 xb = *(const float4*)&X[(size_t)(m0 + 64 + ldRow) * Dn + d0 + ldD];
            float4 ea = *(const float4*)&E[(size_t)(k0 + ldRow)      * Dn + d0 + ldD];
            float4 eb = *(const float4*)&E[(size_t)(k0 + 64 + ldRow) * Dn + d0 + ldD];
            __syncthreads();
            Xs[ldD+0][ldRow] = xa.x; Xs[ldD+1][ldRow] = xa.y;
            Xs[ldD+2][ldRow] = xa.z; Xs[ldD+3][ldRow] = xa.w;
            Xs[ldD+0][64+ldRow] = xb.x; Xs[ldD+1][64+ldRow] = xb.y;
            Xs[ldD+2][64+ldRow] = xb.z; Xs[ldD+3][64+ldRow] = xb.w;
            Es[ldD+0][ldRow] = ea.x; Es[ldD+1][ldRow] = ea.y;
            Es[ldD+2][ldRow] = ea.z; Es[ldD+3][ldRow] = ea.w;
            Es[ldD+0][64+ldRow] = eb.x; Es[ldD+1][64+ldRow] = eb.y;
            Es[ldD+2][64+ldRow] = eb.z; Es[ldD+3][64+ldRow] = eb.w;
            __syncthreads();
            #pragma unroll
            for (int d = 0; d < 16; ++d) {
                float a8[8], b8[8];
                *(float4*)&a8[0] = *(const float4*)&Xs[d][4*ty];
                *(float4*)&a8[4] = *(const float4*)&Xs[d][64 + 4*ty];
                *(float4*)&b8[0] = *(const float4*)&Es[d][4*tx];
                *(float4*)&b8[4] = *(const float4*)&Es[d][64 + 4*tx];
                #pragma unroll
                for (int i = 0; i < 8; ++i)
                    #pragma unroll
                    for (int j = 0; j < 8; ++j) acc[i][j] += a8[i] * b8[j];
            }
        }
        #pragma unroll
        for (int j = 0; j < 8; ++j) {
            const int c = k0 + ((j < 4) ? (4*tx + j) : (64 + 4*tx + (j - 4)));
            const float eq = esq[c];
            #pragma unroll
            for (int i = 0; i < 8; ++i) {
                float dval = eq - 2.0f * acc[i][j];
                if (dval < bestv[i]) { bestv[i] = dval; besti[i] = c; }
            }
        }
    }
    #pragma unroll
    for (int i = 0; i < 8; ++i) {
        int rloc = (i < 4) ? (4*ty + i) : (64 + 4*ty + (i - 4));
        red[rloc][tx] = ((u64)fkey(bestv[i]) << 32) | (u64)(unsigned int)besti[i];
    }
    __syncthreads();
    if (tid < 128) {
        u64 m = red[tid][0];
        #pragma unroll
        for (int t = 1; t < 16; ++t) { u64 v = red[tid][t]; if (v < m) m = v; }
        best[(size_t)(m0 + tid) * KSPLIT + split] = m;
    }
}

__global__ __launch_bounds__(256) void finalize_kernel(
    const float* __restrict__ X, const float* __restrict__ E,
    const u64* __restrict__ best, float* __restrict__ out, int nsplits)
{
    __shared__ int sidx[2];
    const int half = threadIdx.x >> 7;
    const int t    = threadIdx.x & 127;
    const int b    = blockIdx.x * 2 + half;
    if (t < 64) {
        u64 v = (t < nsplits) ? best[(size_t)b * nsplits + t] : ~0ull;
        #pragma unroll
        for (int off = 1; off < 64; off <<= 1) {
            u64 o = __shfl_xor(v, off);
            if (o < v) v = o;
        }
        if (t == 0) {
            int idx = (int)(unsigned int)(v & 0xFFFFFFFFull);
            sidx[half] = idx;
            out[b] = (float)idx;
        }
    }
    __syncthreads();
    const int idx = sidx[half];
    float4 x = ((const float4*)(X + (size_t)b * Dn))[t];
    float4 e = ((const float4*)(E + (size_t)idx * Dn))[t];
    float4 r; r.x = x.x - e.x; r.y = x.y - e.y; r.z = x.z - e.z; r.w = x.w - e.w;
    ((float4*)(out + Bn + (size_t)b * Dn))[t] = r;
}

extern "C" void kernel_launch(void* const* d_in, const int* in_sizes, int n_in,
                              void* d_out, int out_size, void* d_ws, size_t ws_size,
                              hipStream_t stream) {
    const float* X = (const float*)d_in[0];   // previous_residual [B, D]
    const float* E = (const float*)d_in[1];   // codebook_embeddings [K, D]
    float* out = (float*)d_out;               // [B] idx-as-float ++ [B*D] residual

    // fast-path ws: esq 32KB | Xh 8MB | Eh 8MB | bestf 2MB  (~18.3 MB)
    const size_t HB = (size_t)Bn * Dn * sizeof(_Float16);        // 8 MB
    const size_t BESTB = (size_t)Bn * 64 * sizeof(float);        // 2 MB
    const size_t NEED = 32768 + 2 * HB + BESTB;

    float* esq = (float*)d_ws;

    if (ws_size >= NEED) {
        _Float16* Xh = (_Float16*)((char*)d_ws + 32768);
        _Float16* Eh = (_Float16*)((char*)d_ws + 32768 + HB);
        float* bestf = (float*)((char*)d_ws + 32768 + 2 * HB);
        hipMemsetAsync((void*)esq, 0, Kn * sizeof(float), stream);
        convert_hi<<<2048, 256, 0, stream>>>(X, E, Xh, Eh, esq);
        argmin_hi<<<64 * 16, 256, 0, stream>>>(Xh, Eh, esq, bestf);
        refine_kernel<<<Bn / 4, 256, 0, stream>>>(X, E, bestf, out);
    } else {
        u64* best = (u64*)((char*)d_ws + 32768);
        esq_kernel<<<Kn / 4, 256, 0, stream>>>(E, esq);
        argmin_fp32<<<(Bn / 128) * KSPLIT, 256, 0, stream>>>(X, E, esq, best);
        finalize_kernel<<<Bn / 2, 256, 0, stream>>>(X, E, best, out, KSPLIT);
    }
}